// Round 7
// baseline (8901.947 us; speedup 1.0000x reference)
//
#include <hip/hip_runtime.h>
#include <hip/hip_bf16.h>
#include <stdint.h>

typedef unsigned short u16;
typedef unsigned int   u32;
typedef unsigned long long u64;

typedef __attribute__((ext_vector_type(4))) float  f32x4;
typedef __attribute__((ext_vector_type(8))) short  bf16x8;
typedef __attribute__((ext_vector_type(8))) unsigned short us8;

#define T_LEN 2048
#define BATCH 32
#define IDIM  512
#define HDIM  512
#define G4    2048
#define MARK  0x7FC0   // bf16 NaN — impossible output of sigm*tanh (both clamped finite)

// workspace layout (bytes)
#define XBF_OFF   0ull            // bf16 x : 67108864 B (dead after gemm_xp)
#define WIH_OFF   67108864ull     // bf16 wih[2][2048][512] (dead after gemm_xp)
#define HBUF_OFF  67108864ull     // h_hist bf16 [2][4][32][512] = 256 KiB, reuses WIH region
#define WHH_OFF   71303168ull     // bf16 whh[2][2048][512]
#define XP_OFF    75497472ull     // bf16 xp[2][T][w:32][b:32][g:4][u:16]
#define WS_NEED   612499968ull

__device__ __forceinline__ u16 f2bf(float f) {
  u32 u = __float_as_uint(f);
  return (u16)((u + 0x7FFFu + ((u >> 16) & 1u)) >> 16);   // RTNE
}
__device__ __forceinline__ float bf2f(u16 h) {
  return __uint_as_float(((u32)h) << 16);
}
__device__ __forceinline__ float sigm(float x) {
  x = fminf(fmaxf(x, -30.f), 30.f);
  return 1.f / (1.f + __expf(-x));
}
__device__ __forceinline__ float tanh_(float x) {
  x = fminf(fmaxf(x, -15.f), 15.f);
  float e = __expf(2.f * x);
  return (e - 1.f) / (e + 1.f);
}

// ---------------- prep: fp32 -> bf16 conversions (x, weights) ----------------
__global__ __launch_bounds__(256) void prep_kernel(
    const float4* __restrict__ x,
    const float4* __restrict__ wihf, const float4* __restrict__ wihb,
    const float4* __restrict__ whhf, const float4* __restrict__ whhb,
    ushort4* __restrict__ xbf, ushort4* __restrict__ wihbf,
    ushort4* __restrict__ whhbf)
{
  const size_t NX = 8388608, NW = 262144;   // float4 units
  const size_t total = NX + 4 * NW;
  size_t stride = (size_t)gridDim.x * blockDim.x;
  for (size_t i = (size_t)blockIdx.x * blockDim.x + threadIdx.x; i < total; i += stride) {
    const float4* src; ushort4* dst; size_t off;
    if (i < NX)                { src = x;    dst = xbf;          off = i; }
    else if (i < NX + NW)      { src = wihf; dst = wihbf;        off = i - NX; }
    else if (i < NX + 2 * NW)  { src = wihb; dst = wihbf + NW;   off = i - NX - NW; }
    else if (i < NX + 3 * NW)  { src = whhf; dst = whhbf;        off = i - NX - 2 * NW; }
    else                       { src = whhb; dst = whhbf + NW;   off = i - NX - 3 * NW; }
    float4 v = src[off];
    ushort4 o;
    o.x = f2bf(v.x); o.y = f2bf(v.y); o.z = f2bf(v.z); o.w = f2bf(v.w);
    dst[off] = o;
  }
}

// ---------------- prep2 (runs AFTER gemm_xp): seed h_hist into dead WIH region ------------
// layout: hbuf[dir:2][slot:4][32][512] bf16. slot0 = h0, slots 1..3 = MARK.
__global__ __launch_bounds__(256) void prep2_kernel(
    const float4* __restrict__ h0f, const float4* __restrict__ h0b,
    ushort4* __restrict__ hbuf)
{
  size_t i = (size_t)blockIdx.x * blockDim.x + threadIdx.x;   // 32768 ushort4 total
  if (i >= 32768) return;
  const size_t NH = 4096;          // ushort4 per h0 (32*512 u16)
  const size_t DIR = 16384;        // ushort4 per direction (4 slots)
  size_t d = i / DIR, r = i % DIR;
  ushort4 o;
  if (r < NH) {
    float4 v = (d ? h0b : h0f)[r];
    o.x = f2bf(v.x); o.y = f2bf(v.y); o.z = f2bf(v.z); o.w = f2bf(v.w);
  } else {
    o.x = MARK; o.y = MARK; o.z = MARK; o.w = MARK;
  }
  hbuf[i] = o;
}

// ---------------- x-projection GEMM: xp = x @ Wih^T + b (both dirs), permuted store --------
// M=65536 (t*32+b), N=2048, K=512. 128x128 tile, 4 waves, bf16 MFMA. (R1-proven.)
// Store layout per t: [w:32][b:32][g:4][u:16];  col = g*512 + w*16 + u.
__global__ __launch_bounds__(256, 2) void gemm_xp(
    const u16* __restrict__ xbf, const u16* __restrict__ wihbf,
    const float* __restrict__ bias_f, const float* __restrict__ bias_b,
    u16* __restrict__ xpo)
{
  const int m0 = blockIdx.x * 128;
  const int n0 = blockIdx.y * 128;
  const int dir = blockIdx.z;
  const int tid = threadIdx.x, l = tid & 63, wv = tid >> 6;

  __shared__ u16 As[128 * 72];
  __shared__ u16 Bs[128 * 72];

  const u16* wih = wihbf + (size_t)dir * G4 * IDIM;

  f32x4 acc[4][4];
#pragma unroll
  for (int i = 0; i < 4; i++)
#pragma unroll
    for (int j = 0; j < 4; j++) acc[i][j] = (f32x4){0.f, 0.f, 0.f, 0.f};

  const int srow = tid >> 1, shalf = tid & 1;
  const int wr = wv >> 1, wc = wv & 1;

  for (int k0 = 0; k0 < IDIM; k0 += 64) {
    __syncthreads();
    {
      const u16* ag = xbf + (size_t)(m0 + srow) * IDIM + k0 + shalf * 32;
      const u16* bg = wih + (size_t)(n0 + srow) * IDIM + k0 + shalf * 32;
      u16* ad = &As[srow * 72 + shalf * 32];
      u16* bd = &Bs[srow * 72 + shalf * 32];
#pragma unroll
      for (int q = 0; q < 4; q++) *(us8*)(ad + q * 8) = *(const us8*)(ag + q * 8);
#pragma unroll
      for (int q = 0; q < 4; q++) *(us8*)(bd + q * 8) = *(const us8*)(bg + q * 8);
    }
    __syncthreads();
#pragma unroll
    for (int kk = 0; kk < 2; kk++) {
      bf16x8 af[4], bv[4];
#pragma unroll
      for (int i = 0; i < 4; i++)
        af[i] = *(const bf16x8*)&As[(wr * 64 + i * 16 + (l & 15)) * 72 + kk * 32 + (l >> 4) * 8];
#pragma unroll
      for (int j = 0; j < 4; j++)
        bv[j] = *(const bf16x8*)&Bs[(wc * 64 + j * 16 + (l & 15)) * 72 + kk * 32 + (l >> 4) * 8];
#pragma unroll
      for (int i = 0; i < 4; i++)
#pragma unroll
        for (int j = 0; j < 4; j++)
          acc[i][j] = __builtin_amdgcn_mfma_f32_16x16x32_bf16(af[i], bv[j], acc[i][j], 0, 0, 0);
    }
  }

  const float* bias = dir ? bias_b : bias_f;
  const size_t dirbase = (size_t)dir * T_LEN * 65536ull;
#pragma unroll
  for (int j = 0; j < 4; j++) {
    int col = n0 + wc * 64 + j * 16 + (l & 15);
    float bb = bias[col];
    // col = g*512 + w*16 + u  ->  [w:32][b:32][g:4][u:16]
    size_t coloff = (size_t)((col >> 4) & 31) * 2048 + (size_t)(col >> 9) * 16 + (size_t)(col & 15);
#pragma unroll
    for (int i = 0; i < 4; i++) {
#pragma unroll
      for (int r = 0; r < 4; r++) {
        int row = m0 + wr * 64 + i * 16 + (l >> 4) * 4 + r;
        int t = row >> 5, b = row & 31;
        xpo[dirbase + (size_t)t * 65536 + coloff + (size_t)b * 64] = f2bf(acc[i][j][r] + bb);
      }
    }
  }
}

// ---------------- persistent recurrent scan: data-is-the-flag (R4/R6 protocol) ------------
// 64 WGs: dir = bid>>5, w = bid&31. WG owns 16 hidden units x 32 batches.
// Whh slice in registers. 4 waves = (mt: batch-half) x (kh: K-half); K-reduce via LDS,
// parity-double-buffered -> SINGLE barrier per step.
// Tail: 128 threads (b, ug) each produce 4 contiguous units -> publish 8B u64 straight
// from registers (no LDS pack, no 2nd barrier). Clears issued by waves 2/3 right after
// the poll catch (guard: catching h_{k-1} implies all reads of h_{k-2} are done).
__global__ __launch_bounds__(256, 1) void lstm_scan(
    const u16* __restrict__ xp, const u16* __restrict__ whhbf,
    const float* __restrict__ c0f, const float* __restrict__ c0b,
    u16* hbuf, float* __restrict__ out)
{
  const int bid = blockIdx.x;
  const int dir = bid >> 5;
  const int w   = bid & 31;
  const int tid = threadIdx.x, l = tid & 63, wv = tid >> 6;
  const int mt = wv >> 1, kh = wv & 1;        // batch-half, K-half
  const int grp = l >> 4, lr = l & 15;

  __shared__ float Gl[2][2][32][68];          // [parity][kh][batch][g*16+u], padded

  // Whh fragments straight to registers: gate g, K-subtile kk (this wave's K-half)
  bf16x8 bfr[4][8];
#pragma unroll
  for (int g = 0; g < 4; g++) {
    const u16* wrow = whhbf + ((size_t)dir * G4 + (size_t)g * 512 + w * 16 + lr) * 512
                    + kh * 256 + grp * 8;
#pragma unroll
    for (int kk = 0; kk < 8; kk++)
      bfr[g][kk] = *(const bf16x8*)(wrow + kk * 32);
  }

  // elementwise role (tid<128): batch b_, units ug*4 .. ug*4+3
  const int b_ = tid >> 2, ug = tid & 3;
  const float* c0 = dir ? c0b : c0f;
  f32x4 cc = (f32x4){0.f, 0.f, 0.f, 0.f};
  if (tid < 128) {
    const float* cp = c0 + (size_t)b_ * 512 + w * 16 + ug * 4;
    cc[0] = cp[0]; cc[1] = cp[1]; cc[2] = cp[2]; cc[3] = cp[3];
  }
  // clear role (tid>=128)
  const int tb = (tid & 127) >> 2, tg = tid & 3;

  u16* hb = hbuf + (size_t)dir * 4 * BATCH * HDIM;   // 4 slots
  const u16* xpd = xp + (size_t)dir * T_LEN * 65536ull;
  const int arow = mt * 16 + lr;
  const u64 mk64 = 0x7FC07FC07FC07FC0ull;

#define LOAD8                                                              \
    asm volatile(                                                          \
      "global_load_dwordx4 %0, %8, off sc0 sc1\n\t"                        \
      "global_load_dwordx4 %1, %8, off offset:64 sc0 sc1\n\t"              \
      "global_load_dwordx4 %2, %8, off offset:128 sc0 sc1\n\t"             \
      "global_load_dwordx4 %3, %8, off offset:192 sc0 sc1\n\t"             \
      "global_load_dwordx4 %4, %8, off offset:256 sc0 sc1\n\t"             \
      "global_load_dwordx4 %5, %8, off offset:320 sc0 sc1\n\t"             \
      "global_load_dwordx4 %6, %8, off offset:384 sc0 sc1\n\t"             \
      "global_load_dwordx4 %7, %8, off offset:448 sc0 sc1\n\t"             \
      "s_waitcnt vmcnt(0)"                                                 \
      : "=&v"(afr[0]), "=&v"(afr[1]), "=&v"(afr[2]), "=&v"(afr[3]),        \
        "=&v"(afr[4]), "=&v"(afr[5]), "=&v"(afr[6]), "=&v"(afr[7])         \
      : "v"(pbase) : "memory")

  for (int k = 1; k <= T_LEN; k++) {
    const int t = dir ? (T_LEN - k) : (k - 1);
    const int p = k & 1;

    // xp prefetch: 4 u64 (4 gates x 4 units), elementwise threads only
    u64 xq0 = 0, xq1 = 0, xq2 = 0, xq3 = 0;
    if (tid < 128) {
      const u16* xb = xpd + (size_t)t * 65536 + (size_t)w * 2048 + (size_t)b_ * 64 + ug * 4;
      xq0 = *(const u64*)(xb);
      xq1 = *(const u64*)(xb + 16);
      xq2 = *(const u64*)(xb + 32);
      xq3 = *(const u64*)(xb + 48);
    }

    // poll-load h_{k-1}: 8 x 16B chunks; straggler-masked retries
    const u16* pbase = hb + (size_t)((k - 1) & 3) * (BATCH * HDIM)
                     + (size_t)arow * 512 + kh * 256 + grp * 8;
    bf16x8 afr[8];
    LOAD8;
    for (;;) {
      int bad = 0;
#pragma unroll
      for (int q = 0; q < 8; q++) bad |= (afr[q][0] == (short)MARK);
      if (!__any(bad)) break;
      __builtin_amdgcn_s_sleep(1);
      if (bad) { LOAD8; }
    }
    __builtin_amdgcn_sched_barrier(0);

    // clears off the critical path: slot (k+2)&3 holds h_{k-2}; safe now (see header)
    if (tid >= 128) {
      u16* cdst = hb + (size_t)((k + 2) & 3) * (BATCH * HDIM) + (size_t)tb * 512
                + w * 16 + tg * 4;
      asm volatile("global_store_dwordx2 %0, %1, off sc0 sc1" :: "v"(cdst), "v"(mk64) : "memory");
    }

    f32x4 acc[4];
#pragma unroll
    for (int g = 0; g < 4; g++) acc[g] = (f32x4){0.f, 0.f, 0.f, 0.f};
#pragma unroll
    for (int kk = 0; kk < 8; kk++) {
#pragma unroll
      for (int g = 0; g < 4; g++)
        acc[g] = __builtin_amdgcn_mfma_f32_16x16x32_bf16(afr[kk], bfr[g][kk], acc[g], 0, 0, 0);
    }
#pragma unroll
    for (int g = 0; g < 4; g++)
#pragma unroll
      for (int r = 0; r < 4; r++)
        Gl[p][kh][mt * 16 + grp * 4 + r][g * 16 + lr] = acc[g][r];
    __syncthreads();                               // the ONLY barrier per step

    if (tid < 128) {
      f32x4 ga, gf, gg, go;
      {
        f32x4 q0 = *(const f32x4*)&Gl[p][0][b_][0 * 16 + ug * 4];
        f32x4 q1 = *(const f32x4*)&Gl[p][1][b_][0 * 16 + ug * 4];
        ga = q0 + q1;
        q0 = *(const f32x4*)&Gl[p][0][b_][1 * 16 + ug * 4];
        q1 = *(const f32x4*)&Gl[p][1][b_][1 * 16 + ug * 4];
        gf = q0 + q1;
        q0 = *(const f32x4*)&Gl[p][0][b_][2 * 16 + ug * 4];
        q1 = *(const f32x4*)&Gl[p][1][b_][2 * 16 + ug * 4];
        gg = q0 + q1;
        q0 = *(const f32x4*)&Gl[p][0][b_][3 * 16 + ug * 4];
        q1 = *(const f32x4*)&Gl[p][1][b_][3 * 16 + ug * 4];
        go = q0 + q1;
      }
      u16 hu[4];
      f32x4 hv4;
#pragma unroll
      for (int uu = 0; uu < 4; uu++) {
        float ai = ga[uu] + bf2f((u16)(xq0 >> (16 * uu)));
        float af = gf[uu] + bf2f((u16)(xq1 >> (16 * uu)));
        float ag = gg[uu] + bf2f((u16)(xq2 >> (16 * uu)));
        float ao = go[uu] + bf2f((u16)(xq3 >> (16 * uu)));
        float si = sigm(ai), sf_ = sigm(af), sg = tanh_(ag), so = sigm(ao);
        cc[uu] = sf_ * cc[uu] + si * sg;
        float h = so * tanh_(cc[uu]);
        hu[uu] = f2bf(h);
        hv4[uu] = h;
      }
      // publish straight from registers: one 8B sc0 sc1 store
      u32 lo = (u32)hu[0] | ((u32)hu[1] << 16);
      u32 hi = (u32)hu[2] | ((u32)hu[3] << 16);
      u64 hp = ((u64)hi << 32) | (u64)lo;
      u16* dstp = hb + (size_t)(k & 3) * (BATCH * HDIM) + (size_t)b_ * 512 + w * 16 + ug * 4;
      asm volatile("global_store_dwordx2 %0, %1, off sc0 sc1" :: "v"(dstp), "v"(hp) : "memory");
      // output: one float4 store, off the critical path
      *(f32x4*)(out + ((size_t)t * 32 + b_) * 1024 + (size_t)dir * 512 + w * 16 + ug * 4) = hv4;
    }
  }
#undef LOAD8
}

// ---------------------------------------------------------------------------------------
extern "C" void kernel_launch(void* const* d_in, const int* in_sizes, int n_in,
                              void* d_out, int out_size, void* d_ws, size_t ws_size,
                              hipStream_t stream) {
  if (ws_size < WS_NEED) return;

  const float* x     = (const float*)d_in[0];
  const float* h0_f  = (const float*)d_in[1];
  const float* c0_f  = (const float*)d_in[2];
  const float* h0_b  = (const float*)d_in[3];
  const float* c0_b  = (const float*)d_in[4];
  const float* Wih_f = (const float*)d_in[5];
  const float* Whh_f = (const float*)d_in[6];
  const float* b_f   = (const float*)d_in[7];
  const float* Wih_b = (const float*)d_in[8];
  const float* Whh_b = (const float*)d_in[9];
  const float* b_b   = (const float*)d_in[10];

  char* ws = (char*)d_ws;
  u16* xbf   = (u16*)(ws + XBF_OFF);
  u16* wihbf = (u16*)(ws + WIH_OFF);
  u16* whhbf = (u16*)(ws + WHH_OFF);
  u16* xpw   = (u16*)(ws + XP_OFF);
  u16* hbuf  = (u16*)(ws + HBUF_OFF);   // overlays WIH region (dead after gemm_xp)

  prep_kernel<<<4096, 256, 0, stream>>>(
      (const float4*)x, (const float4*)Wih_f, (const float4*)Wih_b,
      (const float4*)Whh_f, (const float4*)Whh_b,
      (ushort4*)xbf, (ushort4*)wihbf, (ushort4*)whhbf);

  dim3 g2(512, 16, 2);
  gemm_xp<<<g2, 256, 0, stream>>>(xbf, wihbf, b_f, b_b, xpw);

  prep2_kernel<<<128, 256, 0, stream>>>(
      (const float4*)h0_f, (const float4*)h0_b, (ushort4*)hbuf);

  lstm_scan<<<64, 256, 0, stream>>>(xpw, whhbf, c0_f, c0_b, hbuf, (float*)d_out);
}

// Round 8
// 8221.591 us; speedup vs baseline: 1.0828x; 1.0828x over previous
//
#include <hip/hip_runtime.h>
#include <hip/hip_bf16.h>
#include <stdint.h>

typedef unsigned short u16;
typedef unsigned int   u32;
typedef unsigned long long u64;

typedef __attribute__((ext_vector_type(4))) float  f32x4;
typedef __attribute__((ext_vector_type(8))) short  bf16x8;
typedef __attribute__((ext_vector_type(8))) unsigned short us8;

#define T_LEN 2048
#define BATCH 32
#define IDIM  512
#define HDIM  512
#define G4    2048
#define MARK  0x7FC0   // bf16 NaN — impossible output of sigm*tanh (both clamped finite)

// workspace layout (bytes)
#define XBF_OFF   0ull            // bf16 x : 67108864 B (dead after gemm_xp)
#define WIH_OFF   67108864ull     // bf16 wih[2][2048][512] (dead after gemm_xp)
#define HBUF_OFF  67108864ull     // h_hist bf16 [2][4][32][512] = 256 KiB, reuses WIH region
#define WHH_OFF   71303168ull     // bf16 whh[2][2048][512]
#define XP_OFF    75497472ull     // bf16 xp[2][T][w:32][b:32][g:4][u:16]
#define WS_NEED   612499968ull

__device__ __forceinline__ u16 f2bf(float f) {
  u32 u = __float_as_uint(f);
  return (u16)((u + 0x7FFFu + ((u >> 16) & 1u)) >> 16);   // RTNE
}
__device__ __forceinline__ float bf2f(u16 h) {
  return __uint_as_float(((u32)h) << 16);
}
__device__ __forceinline__ float sigm(float x) {
  x = fminf(fmaxf(x, -30.f), 30.f);
  return 1.f / (1.f + __expf(-x));
}
__device__ __forceinline__ float tanh_(float x) {
  x = fminf(fmaxf(x, -15.f), 15.f);
  float e = __expf(2.f * x);
  return (e - 1.f) / (e + 1.f);
}

// ---------------- prep: fp32 -> bf16 conversions (x, weights) ----------------
__global__ __launch_bounds__(256) void prep_kernel(
    const float4* __restrict__ x,
    const float4* __restrict__ wihf, const float4* __restrict__ wihb,
    const float4* __restrict__ whhf, const float4* __restrict__ whhb,
    ushort4* __restrict__ xbf, ushort4* __restrict__ wihbf,
    ushort4* __restrict__ whhbf)
{
  const size_t NX = 8388608, NW = 262144;   // float4 units
  const size_t total = NX + 4 * NW;
  size_t stride = (size_t)gridDim.x * blockDim.x;
  for (size_t i = (size_t)blockIdx.x * blockDim.x + threadIdx.x; i < total; i += stride) {
    const float4* src; ushort4* dst; size_t off;
    if (i < NX)                { src = x;    dst = xbf;          off = i; }
    else if (i < NX + NW)      { src = wihf; dst = wihbf;        off = i - NX; }
    else if (i < NX + 2 * NW)  { src = wihb; dst = wihbf + NW;   off = i - NX - NW; }
    else if (i < NX + 3 * NW)  { src = whhf; dst = whhbf;        off = i - NX - 2 * NW; }
    else                       { src = whhb; dst = whhbf + NW;   off = i - NX - 3 * NW; }
    float4 v = src[off];
    ushort4 o;
    o.x = f2bf(v.x); o.y = f2bf(v.y); o.z = f2bf(v.z); o.w = f2bf(v.w);
    dst[off] = o;
  }
}

// ---------------- prep2 (runs AFTER gemm_xp): seed h_hist into dead WIH region ------------
// layout: hbuf[dir:2][slot:4][32][512] bf16. slot0 = h0, slots 1..3 = MARK.
__global__ __launch_bounds__(256) void prep2_kernel(
    const float4* __restrict__ h0f, const float4* __restrict__ h0b,
    ushort4* __restrict__ hbuf)
{
  size_t i = (size_t)blockIdx.x * blockDim.x + threadIdx.x;   // 32768 ushort4 total
  if (i >= 32768) return;
  const size_t NH = 4096;          // ushort4 per h0 (32*512 u16)
  const size_t DIR = 16384;        // ushort4 per direction (4 slots)
  size_t d = i / DIR, r = i % DIR;
  ushort4 o;
  if (r < NH) {
    float4 v = (d ? h0b : h0f)[r];
    o.x = f2bf(v.x); o.y = f2bf(v.y); o.z = f2bf(v.z); o.w = f2bf(v.w);
  } else {
    o.x = MARK; o.y = MARK; o.z = MARK; o.w = MARK;
  }
  hbuf[i] = o;
}

// ---------------- x-projection GEMM: xp = x @ Wih^T + b (both dirs), permuted store --------
// M=65536 (t*32+b), N=2048, K=512. 128x128 tile, 4 waves, bf16 MFMA. (R1-proven.)
// Store layout per t: [w:32][b:32][g:4][u:16];  col = g*512 + w*16 + u.
__global__ __launch_bounds__(256, 2) void gemm_xp(
    const u16* __restrict__ xbf, const u16* __restrict__ wihbf,
    const float* __restrict__ bias_f, const float* __restrict__ bias_b,
    u16* __restrict__ xpo)
{
  const int m0 = blockIdx.x * 128;
  const int n0 = blockIdx.y * 128;
  const int dir = blockIdx.z;
  const int tid = threadIdx.x, l = tid & 63, wv = tid >> 6;

  __shared__ u16 As[128 * 72];
  __shared__ u16 Bs[128 * 72];

  const u16* wih = wihbf + (size_t)dir * G4 * IDIM;

  f32x4 acc[4][4];
#pragma unroll
  for (int i = 0; i < 4; i++)
#pragma unroll
    for (int j = 0; j < 4; j++) acc[i][j] = (f32x4){0.f, 0.f, 0.f, 0.f};

  const int srow = tid >> 1, shalf = tid & 1;
  const int wr = wv >> 1, wc = wv & 1;

  for (int k0 = 0; k0 < IDIM; k0 += 64) {
    __syncthreads();
    {
      const u16* ag = xbf + (size_t)(m0 + srow) * IDIM + k0 + shalf * 32;
      const u16* bg = wih + (size_t)(n0 + srow) * IDIM + k0 + shalf * 32;
      u16* ad = &As[srow * 72 + shalf * 32];
      u16* bd = &Bs[srow * 72 + shalf * 32];
#pragma unroll
      for (int q = 0; q < 4; q++) *(us8*)(ad + q * 8) = *(const us8*)(ag + q * 8);
#pragma unroll
      for (int q = 0; q < 4; q++) *(us8*)(bd + q * 8) = *(const us8*)(bg + q * 8);
    }
    __syncthreads();
#pragma unroll
    for (int kk = 0; kk < 2; kk++) {
      bf16x8 af[4], bv[4];
#pragma unroll
      for (int i = 0; i < 4; i++)
        af[i] = *(const bf16x8*)&As[(wr * 64 + i * 16 + (l & 15)) * 72 + kk * 32 + (l >> 4) * 8];
#pragma unroll
      for (int j = 0; j < 4; j++)
        bv[j] = *(const bf16x8*)&Bs[(wc * 64 + j * 16 + (l & 15)) * 72 + kk * 32 + (l >> 4) * 8];
#pragma unroll
      for (int i = 0; i < 4; i++)
#pragma unroll
        for (int j = 0; j < 4; j++)
          acc[i][j] = __builtin_amdgcn_mfma_f32_16x16x32_bf16(af[i], bv[j], acc[i][j], 0, 0, 0);
    }
  }

  const float* bias = dir ? bias_b : bias_f;
  const size_t dirbase = (size_t)dir * T_LEN * 65536ull;
#pragma unroll
  for (int j = 0; j < 4; j++) {
    int col = n0 + wc * 64 + j * 16 + (l & 15);
    float bb = bias[col];
    // col = g*512 + w*16 + u  ->  [w:32][b:32][g:4][u:16]
    size_t coloff = (size_t)((col >> 4) & 31) * 2048 + (size_t)(col >> 9) * 16 + (size_t)(col & 15);
#pragma unroll
    for (int i = 0; i < 4; i++) {
#pragma unroll
      for (int r = 0; r < 4; r++) {
        int row = m0 + wr * 64 + i * 16 + (l >> 4) * 4 + r;
        int t = row >> 5, b = row & 31;
        xpo[dirbase + (size_t)t * 65536 + coloff + (size_t)b * 64] = f2bf(acc[i][j][r] + bb);
      }
    }
  }
}

// ---------------- persistent recurrent scan: data-is-the-flag (R6 protocol + R7 tail) ----
// 64 WGs: dir = bid>>5, w = bid&31. WG owns 16 hidden units x 32 batches.
// Whh slice in registers. 4 waves = (mt: batch-half) x (kh: K-half); K-reduce via LDS.
// Step: poll (dual-half chunk check, sound for 8B publishes) -> MFMA -> Gl write ->
// barrier1 -> {tid<128: reduce+elementwise+publish-from-regs+out | tid>=128: clears}
// -> barrier2 (throttle: no wave enters next poll before publishes are issued).
__global__ __launch_bounds__(256, 1) void lstm_scan(
    const u16* __restrict__ xp, const u16* __restrict__ whhbf,
    const float* __restrict__ c0f, const float* __restrict__ c0b,
    u16* hbuf, float* __restrict__ out)
{
  const int bid = blockIdx.x;
  const int dir = bid >> 5;
  const int w   = bid & 31;
  const int tid = threadIdx.x, l = tid & 63, wv = tid >> 6;
  const int mt = wv >> 1, kh = wv & 1;        // batch-half, K-half
  const int grp = l >> 4, lr = l & 15;

  __shared__ float Gl[2][32][68];             // [kh][batch][g*16+u], padded

  // Whh fragments straight to registers: gate g, K-subtile kk (this wave's K-half)
  bf16x8 bfr[4][8];
#pragma unroll
  for (int g = 0; g < 4; g++) {
    const u16* wrow = whhbf + ((size_t)dir * G4 + (size_t)g * 512 + w * 16 + lr) * 512
                    + kh * 256 + grp * 8;
#pragma unroll
    for (int kk = 0; kk < 8; kk++)
      bfr[g][kk] = *(const bf16x8*)(wrow + kk * 32);
  }

  // elementwise role (tid<128): batch b_, units ug*4 .. ug*4+3
  const int b_ = tid >> 2, ug = tid & 3;
  const float* c0 = dir ? c0b : c0f;
  f32x4 cc = (f32x4){0.f, 0.f, 0.f, 0.f};
  if (tid < 128) {
    const float* cp = c0 + (size_t)b_ * 512 + w * 16 + ug * 4;
    cc[0] = cp[0]; cc[1] = cp[1]; cc[2] = cp[2]; cc[3] = cp[3];
  }
  // clear role (tid>=128): row tb, units tg*4..tg*4+3
  const int tb = (tid & 127) >> 2, tg = tid & 3;

  u16* hb = hbuf + (size_t)dir * 4 * BATCH * HDIM;   // 4 slots
  const u16* xpd = xp + (size_t)dir * T_LEN * 65536ull;
  const int arow = mt * 16 + lr;
  const u64 mk64 = 0x7FC07FC07FC07FC0ull;

#define LOAD8                                                              \
    asm volatile(                                                          \
      "global_load_dwordx4 %0, %8, off sc0 sc1\n\t"                        \
      "global_load_dwordx4 %1, %8, off offset:64 sc0 sc1\n\t"              \
      "global_load_dwordx4 %2, %8, off offset:128 sc0 sc1\n\t"             \
      "global_load_dwordx4 %3, %8, off offset:192 sc0 sc1\n\t"             \
      "global_load_dwordx4 %4, %8, off offset:256 sc0 sc1\n\t"             \
      "global_load_dwordx4 %5, %8, off offset:320 sc0 sc1\n\t"             \
      "global_load_dwordx4 %6, %8, off offset:384 sc0 sc1\n\t"             \
      "global_load_dwordx4 %7, %8, off offset:448 sc0 sc1\n\t"             \
      "s_waitcnt vmcnt(0)"                                                 \
      : "=&v"(afr[0]), "=&v"(afr[1]), "=&v"(afr[2]), "=&v"(afr[3]),        \
        "=&v"(afr[4]), "=&v"(afr[5]), "=&v"(afr[6]), "=&v"(afr[7])         \
      : "v"(pbase) : "memory")

  for (int k = 1; k <= T_LEN; k++) {
    const int t = dir ? (T_LEN - k) : (k - 1);

    // xp prefetch: 4 u64 (4 gates x 4 units), elementwise threads only
    u64 xq0 = 0, xq1 = 0, xq2 = 0, xq3 = 0;
    if (tid < 128) {
      const u16* xb = xpd + (size_t)t * 65536 + (size_t)w * 2048 + (size_t)b_ * 64 + ug * 4;
      xq0 = *(const u64*)(xb);
      xq1 = *(const u64*)(xb + 16);
      xq2 = *(const u64*)(xb + 32);
      xq3 = *(const u64*)(xb + 48);
    }

    // poll-load h_{k-1}: 8 x 16B chunks; each chunk = two 8B producer stores ->
    // check BOTH halves ([0] and [4]); straggler-masked retries
    const u16* pbase = hb + (size_t)((k - 1) & 3) * (BATCH * HDIM)
                     + (size_t)arow * 512 + kh * 256 + grp * 8;
    bf16x8 afr[8];
    LOAD8;
    for (;;) {
      int bad = 0;
#pragma unroll
      for (int q = 0; q < 8; q++)
        bad |= (afr[q][0] == (short)MARK) | (afr[q][4] == (short)MARK);
      if (!__any(bad)) break;
      __builtin_amdgcn_s_sleep(1);
      if (bad) { LOAD8; }
    }
    __builtin_amdgcn_sched_barrier(0);

    f32x4 acc[4];
#pragma unroll
    for (int g = 0; g < 4; g++) acc[g] = (f32x4){0.f, 0.f, 0.f, 0.f};
#pragma unroll
    for (int kk = 0; kk < 8; kk++) {
#pragma unroll
      for (int g = 0; g < 4; g++)
        acc[g] = __builtin_amdgcn_mfma_f32_16x16x32_bf16(afr[kk], bfr[g][kk], acc[g], 0, 0, 0);
    }
#pragma unroll
    for (int g = 0; g < 4; g++)
#pragma unroll
      for (int r = 0; r < 4; r++)
        Gl[kh][mt * 16 + grp * 4 + r][g * 16 + lr] = acc[g][r];
    __syncthreads();                               // barrier 1: partial gates ready

    if (tid < 128) {
      f32x4 ga, gf, gg, go;
      {
        f32x4 q0 = *(const f32x4*)&Gl[0][b_][0 * 16 + ug * 4];
        f32x4 q1 = *(const f32x4*)&Gl[1][b_][0 * 16 + ug * 4];
        ga = q0 + q1;
        q0 = *(const f32x4*)&Gl[0][b_][1 * 16 + ug * 4];
        q1 = *(const f32x4*)&Gl[1][b_][1 * 16 + ug * 4];
        gf = q0 + q1;
        q0 = *(const f32x4*)&Gl[0][b_][2 * 16 + ug * 4];
        q1 = *(const f32x4*)&Gl[1][b_][2 * 16 + ug * 4];
        gg = q0 + q1;
        q0 = *(const f32x4*)&Gl[0][b_][3 * 16 + ug * 4];
        q1 = *(const f32x4*)&Gl[1][b_][3 * 16 + ug * 4];
        go = q0 + q1;
      }
      u16 hu[4];
      f32x4 hv4;
#pragma unroll
      for (int uu = 0; uu < 4; uu++) {
        float ai = ga[uu] + bf2f((u16)(xq0 >> (16 * uu)));
        float af = gf[uu] + bf2f((u16)(xq1 >> (16 * uu)));
        float ag = gg[uu] + bf2f((u16)(xq2 >> (16 * uu)));
        float ao = go[uu] + bf2f((u16)(xq3 >> (16 * uu)));
        float si = sigm(ai), sf_ = sigm(af), sg = tanh_(ag), so = sigm(ao);
        cc[uu] = sf_ * cc[uu] + si * sg;
        float h = so * tanh_(cc[uu]);
        hu[uu] = f2bf(h);
        hv4[uu] = h;
      }
      // publish straight from registers: one 8B sc0 sc1 store
      u32 lo = (u32)hu[0] | ((u32)hu[1] << 16);
      u32 hi = (u32)hu[2] | ((u32)hu[3] << 16);
      u64 hp = ((u64)hi << 32) | (u64)lo;
      u16* dstp = hb + (size_t)(k & 3) * (BATCH * HDIM) + (size_t)b_ * 512 + w * 16 + ug * 4;
      asm volatile("global_store_dwordx2 %0, %1, off sc0 sc1" :: "v"(dstp), "v"(hp) : "memory");
      // output: one float4 store, off the critical path
      *(f32x4*)(out + ((size_t)t * 32 + b_) * 1024 + (size_t)dir * 512 + w * 16 + ug * 4) = hv4;
    } else {
      // clears, concurrent with elementwise: slot (k+2)&3 holds h_{k-2}; all reads of it
      // are complete (we caught h_{k-1} => every WG caught h_{k-2}). Our own clears are
      // drained by this wave's next-step vmcnt(0), which precedes any k+4 publish.
      u16* cdst = hb + (size_t)((k + 2) & 3) * (BATCH * HDIM) + (size_t)tb * 512
                + w * 16 + tg * 4;
      asm volatile("global_store_dwordx2 %0, %1, off sc0 sc1" :: "v"(cdst), "v"(mk64) : "memory");
    }
    __syncthreads();                               // barrier 2: throttle next-step polls
  }
#undef LOAD8
}

// ---------------------------------------------------------------------------------------
extern "C" void kernel_launch(void* const* d_in, const int* in_sizes, int n_in,
                              void* d_out, int out_size, void* d_ws, size_t ws_size,
                              hipStream_t stream) {
  if (ws_size < WS_NEED) return;

  const float* x     = (const float*)d_in[0];
  const float* h0_f  = (const float*)d_in[1];
  const float* c0_f  = (const float*)d_in[2];
  const float* h0_b  = (const float*)d_in[3];
  const float* c0_b  = (const float*)d_in[4];
  const float* Wih_f = (const float*)d_in[5];
  const float* Whh_f = (const float*)d_in[6];
  const float* b_f   = (const float*)d_in[7];
  const float* Wih_b = (const float*)d_in[8];
  const float* Whh_b = (const float*)d_in[9];
  const float* b_b   = (const float*)d_in[10];

  char* ws = (char*)d_ws;
  u16* xbf   = (u16*)(ws + XBF_OFF);
  u16* wihbf = (u16*)(ws + WIH_OFF);
  u16* whhbf = (u16*)(ws + WHH_OFF);
  u16* xpw   = (u16*)(ws + XP_OFF);
  u16* hbuf  = (u16*)(ws + HBUF_OFF);   // overlays WIH region (dead after gemm_xp)

  prep_kernel<<<4096, 256, 0, stream>>>(
      (const float4*)x, (const float4*)Wih_f, (const float4*)Wih_b,
      (const float4*)Whh_f, (const float4*)Whh_b,
      (ushort4*)xbf, (ushort4*)wihbf, (ushort4*)whhbf);

  dim3 g2(512, 16, 2);
  gemm_xp<<<g2, 256, 0, stream>>>(xbf, wihbf, b_f, b_b, xpw);

  prep2_kernel<<<128, 256, 0, stream>>>(
      (const float4*)h0_f, (const float4*)h0_b, (ushort4*)hbuf);

  lstm_scan<<<64, 256, 0, stream>>>(xpw, whhbf, c0_f, c0_b, hbuf, (float*)d_out);
}